// Round 17
// baseline (169.053 us; speedup 1.0000x reference)
//
#include <hip/hip_runtime.h>
#include <math.h>

#define DEV __device__ __forceinline__

typedef __attribute__((ext_vector_type(4))) float f32x4;
typedef __attribute__((ext_vector_type(8))) __bf16 bf16x8;

static constexpr int Bc = 2, Sc = 2048, Dc = 1024, Hc = 16, HDc = 64;
static constexpr int LDQ = 3 * Dc;                  // fused QKV row stride
static constexpr float SCL = 0.125f * 1.44269504f;  // 1/sqrt(64) * log2(e)

// f32 -> bf16 bits, round-to-nearest-even
DEV unsigned short f2b(float f) {
  union { float f; unsigned int u; } c; c.f = f;
  unsigned int u = c.u;
  unsigned int r = (u + 0x7fffu + ((u >> 16) & 1u)) >> 16;
  return (unsigned short)r;
}

// async global->LDS, 16B per lane; LDS dest = wave-uniform base + lane*16
DEV void async16(const void* g, void* l) {
  __builtin_amdgcn_global_load_lds(
      (__attribute__((address_space(1))) void*)(void*)g,
      (__attribute__((address_space(3))) void*)l, 16, 0, 0);
}

// XOR swizzle for [R][64] bf16 tiles (128B rows)
DEV int swz(int r, int c) { return r * 64 + (c ^ ((r & 7) << 3)); }

// one launch converts X and all four weight matrices to bf16
__global__ void cvt_all(const float* __restrict__ X, const float* __restrict__ Wq,
                        const float* __restrict__ Wk, const float* __restrict__ Wv,
                        const float* __restrict__ Wo,
                        unsigned short* __restrict__ Xb,
                        unsigned short* __restrict__ Wb) {
  const int i = blockIdx.x * blockDim.x + threadIdx.x;  // float4 index
  const float* src;
  unsigned short* dst;
  int o;
  if (i < (1 << 20)) {  // X: 2^20 float4
    src = X; o = i; dst = Xb;
  } else {
    const int wi = i - (1 << 20);
    const int m = wi >> 18;  // 2^18 float4 per weight matrix
    src = m == 0 ? Wq : m == 1 ? Wk : m == 2 ? Wv : Wo;
    o = wi & ((1 << 18) - 1);
    dst = Wb + (size_t)m * (Dc * Dc);
  }
  const float4 v = reinterpret_cast<const float4*>(src)[o];
  ushort4 u;
  u.x = f2b(v.x); u.y = f2b(v.y); u.z = f2b(v.z); u.w = f2b(v.w);
  reinterpret_cast<ushort4*>(dst)[o] = u;
}

// C[M][*] = A[M][K] * Bm[*][K]^T + bias; bias selected per 1024-col group.
// 1D grid with bijective XCD-chunk swizzle (gridDim.x % 8 == 0); M = 4096.
template <typename OUT>
__global__ __launch_bounds__(256, 3) void gemm_bt(
    const unsigned short* __restrict__ A, const unsigned short* __restrict__ Bm,
    const float* __restrict__ b0, const float* __restrict__ b1,
    const float* __restrict__ b2, OUT* __restrict__ C, int M, int K, int ldc) {
  __shared__ unsigned short As[128 * 64];
  __shared__ unsigned short Bs[128 * 64];
  const int tid = threadIdx.x;
  const int wave = tid >> 6, lane = tid & 63;
  const int wr = wave >> 1, wc = wave & 1;
  const int cpx = gridDim.x >> 3;
  const int swzid = (blockIdx.x & 7) * cpx + (blockIdx.x >> 3);
  const int row0 = (swzid & 31) * 128, col0 = (swzid >> 5) * 128;
  const int srow = lane >> 3, scol = (lane & 7) * 8;

  f32x4 acc[4][4];
#pragma unroll
  for (int m = 0; m < 4; ++m)
#pragma unroll
    for (int n = 0; n < 4; ++n) acc[m][n] = {0.f, 0.f, 0.f, 0.f};

  for (int k0 = 0; k0 < K; k0 += 64) {
    __syncthreads();
#pragma unroll
    for (int c = 0; c < 4; ++c) {
      const int rr = (wave * 4 + c) * 8 + srow;
      async16(A + (size_t)(row0 + rr) * K + k0 + scol,
              (char*)As + (wave * 4 + c) * 1024);
      async16(Bm + (size_t)(col0 + rr) * K + k0 + scol,
              (char*)Bs + (wave * 4 + c) * 1024);
    }
    __syncthreads();
#pragma unroll
    for (int ks = 0; ks < 2; ++ks) {
      const int kk = ks * 32 + (lane >> 4) * 8;
      bf16x8 af[4], bfr[4];
#pragma unroll
      for (int m = 0; m < 4; ++m)
        af[m] = *reinterpret_cast<const bf16x8*>(
            &As[(wr * 64 + m * 16 + (lane & 15)) * 64 + kk]);
#pragma unroll
      for (int n = 0; n < 4; ++n)
        bfr[n] = *reinterpret_cast<const bf16x8*>(
            &Bs[(wc * 64 + n * 16 + (lane & 15)) * 64 + kk]);
#pragma unroll
      for (int m = 0; m < 4; ++m)
#pragma unroll
        for (int n = 0; n < 4; ++n)
          acc[m][n] = __builtin_amdgcn_mfma_f32_16x16x32_bf16(af[m], bfr[n],
                                                              acc[m][n], 0, 0, 0);
    }
  }
  const int r4 = (lane >> 4) * 4, cl = lane & 15;
#pragma unroll
  for (int n = 0; n < 4; ++n) {
    const int gc = col0 + wc * 64 + n * 16 + cl;
    const float* bp = gc < Dc ? b0 : (gc < 2 * Dc ? b1 : b2);
    const float bv = bp[gc & (Dc - 1)];
#pragma unroll
    for (int m = 0; m < 4; ++m) {
#pragma unroll
      for (int j = 0; j < 4; ++j) {
        const int gr = row0 + wr * 64 + m * 16 + r4 + j;
        const float v = acc[m][n][j] + bv;
        if constexpr (sizeof(OUT) == 4)
          C[(size_t)gr * ldc + gc] = v;
        else
          C[(size_t)gr * ldc + gc] = (OUT)f2b(v);
      }
    }
  }
}

// flash attention, 2-phase pipelined. K and Q fragments load DIRECTLY from
// global (L2-resident: co-resident blocks share (b,h)) -> no K/Q LDS staging,
// no ds_reads for K, barrier only drains V writes. LDS 24 KB.
__global__ __launch_bounds__(256, 4) void attn_fwd(
    const __bf16* __restrict__ Qg, const __bf16* __restrict__ Kg,
    const __bf16* __restrict__ Vg, const int* __restrict__ kpm,
    __bf16* __restrict__ Og) {
  __shared__ __bf16 Ps_all[4 * 16 * 64];  // per-wave P tiles (8 KB)
  __shared__ __bf16 Vt[2][64 * 64];       // double-buffered V^T [d][k] (16 KB)

  // balanced work mapping: L = s*256 + c; slots on one CU sum qb to 62
  const int L = blockIdx.x;
  const int s = L >> 8, c = L & 255;
  const int u = c >> 5, bh = c & 31;
  const int qb = s * 8 + ((s & 1) ? (7 - u) : u);

  const int b = bh >> 4, h = bh & 15;
  const int q0 = qb * 64;
  const int tid = threadIdx.x, wave = tid >> 6, lane = tid & 63;
  const size_t base = (size_t)b * Sc * LDQ + (size_t)h * HDc;
  const int hi = lane >> 4, cl = lane & 15, r4 = hi * 4;

  // V loader: 2 k-rows x 8 d per thread; packed b32 swizzled writes
  const int vk2 = (tid & 31) * 2, vd8 = (tid >> 5) * 8;
  const __bf16* vbase = Vg + base + (size_t)vk2 * LDQ + vd8;
  const int* mbase = kpm + b * Sc;

  union VV { uint4 q; unsigned short u[8]; };

  // Q fragments direct from global (two aligned 16B loads per lane)
  const __bf16* qrow =
      Qg + base + (size_t)(q0 + wave * 16 + cl) * LDQ + hi * 8;
  bf16x8 qf[2];
  qf[0] = *reinterpret_cast<const bf16x8*>(qrow);
  qf[1] = *reinterpret_cast<const bf16x8*>(qrow + 32);

  // K fragment base: frag (ks,n) at tile kb -> kfb + (kb*64 + n*16)*LDQ + ks*32
  const __bf16* kfb = Kg + base + (size_t)cl * LDQ + hi * 8;

  // prologue: V0 + mask0 (regs) -> Vt[0]
  VV v0, v1;
  v0.q = *reinterpret_cast<const uint4*>(vbase);
  v1.q = *reinterpret_cast<const uint4*>(vbase + LDQ);
  int mki[4];
#pragma unroll
  for (int n = 0; n < 4; ++n) mki[n] = mbase[n * 16 + cl];
  {
    unsigned int* V32 = reinterpret_cast<unsigned int*>(Vt[0]);
#pragma unroll
    for (int i = 0; i < 8; ++i) {
      const int row = vd8 + i;
      V32[row * 32 + ((tid & 31) ^ ((row & 7) << 2))] =
          (unsigned int)v0.u[i] | ((unsigned int)v1.u[i] << 16);
    }
  }
  __bf16* Ps = Ps_all + wave * 1024;  // per-wave 16x64 P tile

  bf16x8 ones;
#pragma unroll
  for (int i = 0; i < 8; ++i) ones[i] = (__bf16)1.0f;

  f32x4 o[4], lacc;
  float m_[4];
#pragma unroll
  for (int n = 0; n < 4; ++n) o[n] = {0.f, 0.f, 0.f, 0.f};
  lacc = {0.f, 0.f, 0.f, 0.f};
#pragma unroll
  for (int j = 0; j < 4; ++j) m_[j] = -1e30f;

  __syncthreads();

  int pb = 0;
  for (int kb = 0; kb <= qb; ++kb) {
    const bool diag = (kb == qb);  // last tile is the diagonal tile
    VV n0, n1;
    int nmk[4];
    if (!diag) {  // prefetch next V tile + mask into regs (hides under compute)
      const int k1 = (kb + 1) * 64;
      n0.q = *reinterpret_cast<const uint4*>(vbase + (size_t)k1 * LDQ);
      n1.q = *reinterpret_cast<const uint4*>(vbase + (size_t)(k1 + 1) * LDQ);
#pragma unroll
      for (int n = 0; n < 4; ++n) nmk[n] = mbase[k1 + n * 16 + cl];
    }

    // K fragments for this tile, direct from global (8 x 16B, L2-resident)
    bf16x8 kf[2][4];
#pragma unroll
    for (int ks = 0; ks < 2; ++ks)
#pragma unroll
      for (int n = 0; n < 4; ++n)
        kf[ks][n] = *reinterpret_cast<const bf16x8*>(
            kfb + (size_t)(kb * 64 + n * 16) * LDQ + ks * 32);

    // S = Q K^T
    f32x4 sa[4];
#pragma unroll
    for (int n = 0; n < 4; ++n) sa[n] = {0.f, 0.f, 0.f, 0.f};
    __builtin_amdgcn_s_setprio(1);
#pragma unroll
    for (int ks = 0; ks < 2; ++ks) {
#pragma unroll
      for (int n = 0; n < 4; ++n) {
        if (!(diag && n > wave)) {  // frags fully above diagonal: skip
          sa[n] = __builtin_amdgcn_mfma_f32_16x16x32_bf16(qf[ks], kf[ks][n],
                                                          sa[n], 0, 0, 0);
        }
      }
    }
    __builtin_amdgcn_s_setprio(0);
    // scale (base-2) + pad mask + causal (diag only) + partial max
    float pm[4] = {-1e30f, -1e30f, -1e30f, -1e30f};
#pragma unroll
    for (int n = 0; n < 4; ++n) {
      const float mf = mki[n] ? -1e30f : 0.0f;
#pragma unroll
      for (int j = 0; j < 4; ++j) {
        float s2 = fmaf(sa[n][j], SCL, mf);
        if (diag && (kb * 64 + n * 16 + cl > q0 + wave * 16 + r4 + j))
          s2 = -1e30f;
        sa[n][j] = s2;
        pm[j] = fmaxf(pm[j], s2);
      }
    }
    // defer-max: rescale only when some row grew by > 8 (base-2 units)
    const bool ok = (pm[0] - m_[0] <= 8.f) && (pm[1] - m_[1] <= 8.f) &&
                    (pm[2] - m_[2] <= 8.f) && (pm[3] - m_[3] <= 8.f);
    if (!__all(ok)) {
#pragma unroll
      for (int off = 1; off < 16; off <<= 1)
#pragma unroll
        for (int j = 0; j < 4; ++j)
          pm[j] = fmaxf(pm[j], __shfl_xor(pm[j], off, 64));
#pragma unroll
      for (int j = 0; j < 4; ++j) {
        const float mn = fmaxf(m_[j], pm[j]);
        const float sc = __builtin_amdgcn_exp2f(m_[j] - mn);
        m_[j] = mn;
        lacc[j] *= sc;
#pragma unroll
        for (int n = 0; n < 4; ++n) o[n][j] *= sc;
      }
    }
    // P = 2^(s2 - m) -> per-wave LDS tile
#pragma unroll
    for (int n = 0; n < 4; ++n)
#pragma unroll
      for (int j = 0; j < 4; ++j) {
        const float p = __builtin_amdgcn_exp2f(sa[n][j] - m_[j]);
        Ps[swz(r4 + j, n * 16 + cl)] = (__bf16)p;
      }
    // O += P V ; l += P * 1
    __builtin_amdgcn_s_setprio(1);
#pragma unroll
    for (int ks = 0; ks < 2; ++ks) {
      const int kk = ks * 32 + hi * 8;
      const bf16x8 pf = *reinterpret_cast<const bf16x8*>(&Ps[swz(cl, kk)]);
#pragma unroll
      for (int n = 0; n < 4; ++n) {
        const bf16x8 vf = *reinterpret_cast<const bf16x8*>(
            &Vt[pb][swz(n * 16 + cl, kk)]);
        o[n] = __builtin_amdgcn_mfma_f32_16x16x32_bf16(pf, vf, o[n], 0, 0, 0);
      }
      lacc = __builtin_amdgcn_mfma_f32_16x16x32_bf16(pf, ones, lacc, 0, 0, 0);
    }
    __builtin_amdgcn_s_setprio(0);
    // write next V (loads had the whole tile to land) + rotate mask
    if (!diag) {
      unsigned int* V32 = reinterpret_cast<unsigned int*>(Vt[pb ^ 1]);
#pragma unroll
      for (int i = 0; i < 8; ++i) {
        const int row = vd8 + i;
        V32[row * 32 + ((tid & 31) ^ ((row & 7) << 2))] =
            (unsigned int)n0.u[i] | ((unsigned int)n1.u[i] << 16);
      }
#pragma unroll
      for (int n = 0; n < 4; ++n) mki[n] = nmk[n];
    }
    __syncthreads();  // drains V ds_writes (lgkm)
    pb ^= 1;
  }

#pragma unroll
  for (int j = 0; j < 4; ++j) {
    const float inv = 1.f / lacc[j];
#pragma unroll
    for (int n = 0; n < 4; ++n)
      Og[(size_t)(b * Sc + q0 + wave * 16 + r4 + j) * Dc + h * HDc + n * 16 +
         cl] = (__bf16)(o[n][j] * inv);
  }
}

extern "C" void kernel_launch(void* const* d_in, const int* in_sizes, int n_in,
                              void* d_out, int out_size, void* d_ws,
                              size_t ws_size, hipStream_t stream) {
  const float* X = (const float*)d_in[0];
  const int* kpm = (const int*)d_in[1];
  const float* Wq = (const float*)d_in[2];
  const float* bq = (const float*)d_in[3];
  const float* Wk = (const float*)d_in[4];
  const float* bk = (const float*)d_in[5];
  const float* Wv = (const float*)d_in[6];
  const float* bv = (const float*)d_in[7];
  const float* Wo = (const float*)d_in[8];
  const float* bo = (const float*)d_in[9];
  float* out = (float*)d_out;

  char* w = (char*)d_ws;
  unsigned short* Xb = (unsigned short*)(w);                  // 8 MB
  unsigned short* Wqkvb = (unsigned short*)(w + (8u << 20));  // 6 MB (q,k,v)
  unsigned short* Wob = (unsigned short*)(w + (14u << 20));   // 2 MB
  unsigned short* QKVb = (unsigned short*)(w + (16u << 20));  // 24 MB
  unsigned short* Ab = (unsigned short*)(w + (40u << 20));    // 8 MB -> 48 MB

  const int MD = Bc * Sc;  // 4096
  // X (2^20 float4) + 4 weights (4 * 2^18 float4) in one launch
  cvt_all<<<dim3(8192), 256, 0, stream>>>(X, Wq, Wk, Wv, Wo, Xb, Wqkvb);

  // fused QKV projection: C is [4096][3072]; 768 blocks (96/XCD)
  gemm_bt<unsigned short><<<dim3(32 * 24), 256, 0, stream>>>(
      Xb, Wqkvb, bq, bk, bv, QKVb, MD, Dc, LDQ);

  attn_fwd<<<dim3(1024), 256, 0, stream>>>(
      (const __bf16*)QKVb, (const __bf16*)QKVb + Dc,
      (const __bf16*)QKVb + 2 * Dc, kpm, (__bf16*)Ab);

  // output projection: 256 blocks (32/XCD)
  gemm_bt<float><<<dim3(32 * 8), 256, 0, stream>>>(
      Ab, Wob, bo, bo, bo, out, MD, Dc, Dc);
}

// Round 18
// 119.960 us; speedup vs baseline: 1.4092x; 1.4092x over previous
//
#include <hip/hip_runtime.h>
#include <math.h>

#define DEV __device__ __forceinline__

typedef __attribute__((ext_vector_type(4))) float f32x4;
typedef __attribute__((ext_vector_type(8))) __bf16 bf16x8;

static constexpr int Bc = 2, Sc = 2048, Dc = 1024, Hc = 16, HDc = 64;
static constexpr int LDQ = 3 * Dc;                  // fused QKV row stride
static constexpr float SCL = 0.125f * 1.44269504f;  // 1/sqrt(64) * log2(e)

// f32 -> bf16 bits, round-to-nearest-even
DEV unsigned short f2b(float f) {
  union { float f; unsigned int u; } c; c.f = f;
  unsigned int u = c.u;
  unsigned int r = (u + 0x7fffu + ((u >> 16) & 1u)) >> 16;
  return (unsigned short)r;
}

// async global->LDS, 16B per lane; LDS dest = wave-uniform base + lane*16
DEV void async16(const void* g, void* l) {
  __builtin_amdgcn_global_load_lds(
      (__attribute__((address_space(1))) void*)(void*)g,
      (__attribute__((address_space(3))) void*)l, 16, 0, 0);
}

// XOR swizzle for [R][64] bf16 tiles (128B rows)
DEV int swz(int r, int c) { return r * 64 + (c ^ ((r & 7) << 3)); }

// one launch converts X and all four weight matrices to bf16
__global__ void cvt_all(const float* __restrict__ X, const float* __restrict__ Wq,
                        const float* __restrict__ Wk, const float* __restrict__ Wv,
                        const float* __restrict__ Wo,
                        unsigned short* __restrict__ Xb,
                        unsigned short* __restrict__ Wb) {
  const int i = blockIdx.x * blockDim.x + threadIdx.x;  // float4 index
  const float* src;
  unsigned short* dst;
  int o;
  if (i < (1 << 20)) {  // X: 2^20 float4
    src = X; o = i; dst = Xb;
  } else {
    const int wi = i - (1 << 20);
    const int m = wi >> 18;  // 2^18 float4 per weight matrix
    src = m == 0 ? Wq : m == 1 ? Wk : m == 2 ? Wv : Wo;
    o = wi & ((1 << 18) - 1);
    dst = Wb + (size_t)m * (Dc * Dc);
  }
  const float4 v = reinterpret_cast<const float4*>(src)[o];
  ushort4 u;
  u.x = f2b(v.x); u.y = f2b(v.y); u.z = f2b(v.z); u.w = f2b(v.w);
  reinterpret_cast<ushort4*>(dst)[o] = u;
}

// C[M][*] = A[M][K] * Bm[*][K]^T + bias; bias selected per 1024-col group.
// 1D grid with bijective XCD-chunk swizzle (gridDim.x % 8 == 0); M = 4096.
template <typename OUT>
__global__ __launch_bounds__(256, 3) void gemm_bt(
    const unsigned short* __restrict__ A, const unsigned short* __restrict__ Bm,
    const float* __restrict__ b0, const float* __restrict__ b1,
    const float* __restrict__ b2, OUT* __restrict__ C, int M, int K, int ldc) {
  __shared__ unsigned short As[128 * 64];
  __shared__ unsigned short Bs[128 * 64];
  const int tid = threadIdx.x;
  const int wave = tid >> 6, lane = tid & 63;
  const int wr = wave >> 1, wc = wave & 1;
  const int cpx = gridDim.x >> 3;
  const int swzid = (blockIdx.x & 7) * cpx + (blockIdx.x >> 3);
  const int row0 = (swzid & 31) * 128, col0 = (swzid >> 5) * 128;
  const int srow = lane >> 3, scol = (lane & 7) * 8;

  f32x4 acc[4][4];
#pragma unroll
  for (int m = 0; m < 4; ++m)
#pragma unroll
    for (int n = 0; n < 4; ++n) acc[m][n] = {0.f, 0.f, 0.f, 0.f};

  for (int k0 = 0; k0 < K; k0 += 64) {
    __syncthreads();
#pragma unroll
    for (int c = 0; c < 4; ++c) {
      const int rr = (wave * 4 + c) * 8 + srow;
      async16(A + (size_t)(row0 + rr) * K + k0 + scol,
              (char*)As + (wave * 4 + c) * 1024);
      async16(Bm + (size_t)(col0 + rr) * K + k0 + scol,
              (char*)Bs + (wave * 4 + c) * 1024);
    }
    __syncthreads();
#pragma unroll
    for (int ks = 0; ks < 2; ++ks) {
      const int kk = ks * 32 + (lane >> 4) * 8;
      bf16x8 af[4], bfr[4];
#pragma unroll
      for (int m = 0; m < 4; ++m)
        af[m] = *reinterpret_cast<const bf16x8*>(
            &As[(wr * 64 + m * 16 + (lane & 15)) * 64 + kk]);
#pragma unroll
      for (int n = 0; n < 4; ++n)
        bfr[n] = *reinterpret_cast<const bf16x8*>(
            &Bs[(wc * 64 + n * 16 + (lane & 15)) * 64 + kk]);
#pragma unroll
      for (int m = 0; m < 4; ++m)
#pragma unroll
        for (int n = 0; n < 4; ++n)
          acc[m][n] = __builtin_amdgcn_mfma_f32_16x16x32_bf16(af[m], bfr[n],
                                                              acc[m][n], 0, 0, 0);
    }
  }
  const int r4 = (lane >> 4) * 4, cl = lane & 15;
#pragma unroll
  for (int n = 0; n < 4; ++n) {
    const int gc = col0 + wc * 64 + n * 16 + cl;
    const float* bp = gc < Dc ? b0 : (gc < 2 * Dc ? b1 : b2);
    const float bv = bp[gc & (Dc - 1)];
#pragma unroll
    for (int m = 0; m < 4; ++m) {
#pragma unroll
      for (int j = 0; j < 4; ++j) {
        const int gr = row0 + wr * 64 + m * 16 + r4 + j;
        const float v = acc[m][n][j] + bv;
        if constexpr (sizeof(OUT) == 4)
          C[(size_t)gr * ldc + gc] = v;
        else
          C[(size_t)gr * ldc + gc] = (OUT)f2b(v);
      }
    }
  }
}

// flash attention, 2-phase pipelined (measured-best Round-9 configuration:
// int kpm mask, row-layout softmax, balanced per-CU work mapping).
__global__ __launch_bounds__(256, 4) void attn_fwd(
    const __bf16* __restrict__ Qg, const __bf16* __restrict__ Kg,
    const __bf16* __restrict__ Vg, const int* __restrict__ kpm,
    __bf16* __restrict__ Og) {
  __shared__ __bf16 QP[64 * 64];     // Q tile, reused as per-wave P tiles
  __shared__ __bf16 Ks[2][64 * 64];  // double-buffered K
  __shared__ __bf16 Vt[2][64 * 64];  // double-buffered V^T [d][k]

  // balanced work mapping: L = s*256 + c; slots on one CU sum qb to 62
  const int L = blockIdx.x;
  const int s = L >> 8, c = L & 255;
  const int u = c >> 5, bh = c & 31;
  const int qb = s * 8 + ((s & 1) ? (7 - u) : u);

  const int b = bh >> 4, h = bh & 15;
  const int q0 = qb * 64;
  const int tid = threadIdx.x, wave = tid >> 6, lane = tid & 63;
  const size_t base = (size_t)b * Sc * LDQ + (size_t)h * HDc;
  const int srow = lane >> 3;
  const int scol = 8 * ((lane & 7) ^ srow);  // inverse-swizzled source col
  const int hi = lane >> 4, cl = lane & 15, r4 = hi * 4;

  // V loader: 2 k-rows x 8 d per thread; packed b32 swizzled writes
  const int vk2 = (tid & 31) * 2, vd8 = (tid >> 5) * 8;
  const __bf16* vbase = Vg + base + (size_t)vk2 * LDQ + vd8;
  const int* mbase = kpm + b * Sc;

  union VV { uint4 q; unsigned short u[8]; };

  // prologue: stage Q + K0 (async), V0 + mask0 (regs)
#pragma unroll
  for (int cc = 0; cc < 2; ++cc) {
    const int rr = (wave * 2 + cc) * 8 + srow;
    async16(Qg + base + (size_t)(q0 + rr) * LDQ + scol,
            (char*)QP + (wave * 2 + cc) * 1024);
    async16(Kg + base + (size_t)rr * LDQ + scol,
            (char*)Ks[0] + (wave * 2 + cc) * 1024);
  }
  VV v0, v1;
  v0.q = *reinterpret_cast<const uint4*>(vbase);
  v1.q = *reinterpret_cast<const uint4*>(vbase + LDQ);
  int mki[4];
#pragma unroll
  for (int n = 0; n < 4; ++n) mki[n] = mbase[n * 16 + cl];
  {
    unsigned int* V32 = reinterpret_cast<unsigned int*>(Vt[0]);
#pragma unroll
    for (int i = 0; i < 8; ++i) {
      const int row = vd8 + i;
      V32[row * 32 + ((tid & 31) ^ ((row & 7) << 2))] =
          (unsigned int)v0.u[i] | ((unsigned int)v1.u[i] << 16);
    }
  }
  __syncthreads();

  bf16x8 qf[2];
#pragma unroll
  for (int ks = 0; ks < 2; ++ks)
    qf[ks] = *reinterpret_cast<const bf16x8*>(
        &QP[swz(wave * 16 + cl, ks * 32 + hi * 8)]);
  __bf16* Ps = QP + wave * 1024;  // per-wave 16x64 P tile

  bf16x8 ones;
#pragma unroll
  for (int i = 0; i < 8; ++i) ones[i] = (__bf16)1.0f;

  f32x4 o[4], lacc;
  float m_[4];
#pragma unroll
  for (int n = 0; n < 4; ++n) o[n] = {0.f, 0.f, 0.f, 0.f};
  lacc = {0.f, 0.f, 0.f, 0.f};
#pragma unroll
  for (int j = 0; j < 4; ++j) m_[j] = -1e30f;

  int pb = 0;
  for (int kb = 0; kb <= qb; ++kb) {
    const bool diag = (kb == qb);  // last tile is the diagonal tile
    VV n0, n1;
    int nmk[4];
    if (!diag) {  // issue next tile's stage FIRST (hides under compute)
      const int k1 = (kb + 1) * 64;
#pragma unroll
      for (int cc = 0; cc < 2; ++cc) {
        const int rr = (wave * 2 + cc) * 8 + srow;
        async16(Kg + base + (size_t)(k1 + rr) * LDQ + scol,
                (char*)Ks[pb ^ 1] + (wave * 2 + cc) * 1024);
      }
      n0.q = *reinterpret_cast<const uint4*>(vbase + (size_t)k1 * LDQ);
      n1.q = *reinterpret_cast<const uint4*>(vbase + (size_t)(k1 + 1) * LDQ);
#pragma unroll
      for (int n = 0; n < 4; ++n) nmk[n] = mbase[k1 + n * 16 + cl];
    }

    // S = Q K^T from Ks[pb]
    f32x4 sa[4];
#pragma unroll
    for (int n = 0; n < 4; ++n) sa[n] = {0.f, 0.f, 0.f, 0.f};
    __builtin_amdgcn_s_setprio(1);
#pragma unroll
    for (int ks = 0; ks < 2; ++ks) {
      const int kk = ks * 32 + hi * 8;
#pragma unroll
      for (int n = 0; n < 4; ++n) {
        if (!(diag && n > wave)) {  // frags fully above diagonal: skip
          const bf16x8 kf = *reinterpret_cast<const bf16x8*>(
              &Ks[pb][swz(n * 16 + cl, kk)]);
          sa[n] = __builtin_amdgcn_mfma_f32_16x16x32_bf16(qf[ks], kf, sa[n],
                                                          0, 0, 0);
        }
      }
    }
    __builtin_amdgcn_s_setprio(0);
    // scale (base-2) + pad mask + causal (diag only) + partial max
    float pm[4] = {-1e30f, -1e30f, -1e30f, -1e30f};
#pragma unroll
    for (int n = 0; n < 4; ++n) {
      const float mf = mki[n] ? -1e30f : 0.0f;
#pragma unroll
      for (int j = 0; j < 4; ++j) {
        float s2 = fmaf(sa[n][j], SCL, mf);
        if (diag && (kb * 64 + n * 16 + cl > q0 + wave * 16 + r4 + j))
          s2 = -1e30f;
        sa[n][j] = s2;
        pm[j] = fmaxf(pm[j], s2);
      }
    }
    // defer-max: rescale only when some row grew by > 8 (base-2 units)
    const bool ok = (pm[0] - m_[0] <= 8.f) && (pm[1] - m_[1] <= 8.f) &&
                    (pm[2] - m_[2] <= 8.f) && (pm[3] - m_[3] <= 8.f);
    if (!__all(ok)) {
#pragma unroll
      for (int off = 1; off < 16; off <<= 1)
#pragma unroll
        for (int j = 0; j < 4; ++j)
          pm[j] = fmaxf(pm[j], __shfl_xor(pm[j], off, 64));
#pragma unroll
      for (int j = 0; j < 4; ++j) {
        const float mn = fmaxf(m_[j], pm[j]);
        const float sc = __builtin_amdgcn_exp2f(m_[j] - mn);
        m_[j] = mn;
        lacc[j] *= sc;
#pragma unroll
        for (int n = 0; n < 4; ++n) o[n][j] *= sc;
      }
    }
    // P = 2^(s2 - m) -> per-wave LDS tile
#pragma unroll
    for (int n = 0; n < 4; ++n)
#pragma unroll
      for (int j = 0; j < 4; ++j) {
        const float p = __builtin_amdgcn_exp2f(sa[n][j] - m_[j]);
        Ps[swz(r4 + j, n * 16 + cl)] = (__bf16)p;
      }
    // O += P V ; l += P * 1
    __builtin_amdgcn_s_setprio(1);
#pragma unroll
    for (int ks = 0; ks < 2; ++ks) {
      const int kk = ks * 32 + hi * 8;
      const bf16x8 pf = *reinterpret_cast<const bf16x8*>(&Ps[swz(cl, kk)]);
#pragma unroll
      for (int n = 0; n < 4; ++n) {
        const bf16x8 vf = *reinterpret_cast<const bf16x8*>(
            &Vt[pb][swz(n * 16 + cl, kk)]);
        o[n] = __builtin_amdgcn_mfma_f32_16x16x32_bf16(pf, vf, o[n], 0, 0, 0);
      }
      lacc = __builtin_amdgcn_mfma_f32_16x16x32_bf16(pf, ones, lacc, 0, 0, 0);
    }
    __builtin_amdgcn_s_setprio(0);
    // write next V (loads had the whole tile to land) + rotate mask
    if (!diag) {
      unsigned int* V32 = reinterpret_cast<unsigned int*>(Vt[pb ^ 1]);
#pragma unroll
      for (int i = 0; i < 8; ++i) {
        const int row = vd8 + i;
        V32[row * 32 + ((tid & 31) ^ ((row & 7) << 2))] =
            (unsigned int)n0.u[i] | ((unsigned int)n1.u[i] << 16);
      }
#pragma unroll
      for (int n = 0; n < 4; ++n) mki[n] = nmk[n];
    }
    __syncthreads();  // drains K-async (vmcnt) + V ds_writes (lgkm)
    pb ^= 1;
  }

#pragma unroll
  for (int j = 0; j < 4; ++j) {
    const float inv = 1.f / lacc[j];
#pragma unroll
    for (int n = 0; n < 4; ++n)
      Og[(size_t)(b * Sc + q0 + wave * 16 + r4 + j) * Dc + h * HDc + n * 16 +
         cl] = (__bf16)(o[n][j] * inv);
  }
}

extern "C" void kernel_launch(void* const* d_in, const int* in_sizes, int n_in,
                              void* d_out, int out_size, void* d_ws,
                              size_t ws_size, hipStream_t stream) {
  const float* X = (const float*)d_in[0];
  const int* kpm = (const int*)d_in[1];
  const float* Wq = (const float*)d_in[2];
  const float* bq = (const float*)d_in[3];
  const float* Wk = (const float*)d_in[4];
  const float* bk = (const float*)d_in[5];
  const float* Wv = (const float*)d_in[6];
  const float* bv = (const float*)d_in[7];
  const float* Wo = (const float*)d_in[8];
  const float* bo = (const float*)d_in[9];
  float* out = (float*)d_out;

  char* w = (char*)d_ws;
  unsigned short* Xb = (unsigned short*)(w);                  // 8 MB
  unsigned short* Wqkvb = (unsigned short*)(w + (8u << 20));  // 6 MB (q,k,v)
  unsigned short* Wob = (unsigned short*)(w + (14u << 20));   // 2 MB
  unsigned short* QKVb = (unsigned short*)(w + (16u << 20));  // 24 MB
  unsigned short* Ab = (unsigned short*)(w + (40u << 20));    // 8 MB -> 48 MB

  const int MD = Bc * Sc;  // 4096
  // X (2^20 float4) + 4 weights (4 * 2^18 float4) in one launch
  cvt_all<<<dim3(8192), 256, 0, stream>>>(X, Wq, Wk, Wv, Wo, Xb, Wqkvb);

  // fused QKV projection: C is [4096][3072]; 768 blocks (96/XCD)
  gemm_bt<unsigned short><<<dim3(32 * 24), 256, 0, stream>>>(
      Xb, Wqkvb, bq, bk, bv, QKVb, MD, Dc, LDQ);

  attn_fwd<<<dim3(1024), 256, 0, stream>>>(
      (const __bf16*)QKVb, (const __bf16*)QKVb + Dc,
      (const __bf16*)QKVb + 2 * Dc, kpm, (__bf16*)Ab);

  // output projection: 256 blocks (32/XCD)
  gemm_bt<float><<<dim3(32 * 8), 256, 0, stream>>>(
      Ab, Wob, bo, bo, bo, out, MD, Dc, Dc);
}